// Round 1
// baseline (126.942 us; speedup 1.0000x reference)
//
#include <hip/hip_runtime.h>
#include <cstdint>
#include <cstddef>

// Problem constants (from reference setup_inputs)
#define NB 8
#define CH 256
#define DD 8
#define HH 16
#define WW 16
#define PP 2048          // D*H*W ; one z-slab = HH*WW = 256 voxels

// Workspace layout (bytes):
//   [0,     16384)   float partial[NB*8*16*4]  (per-wave numerator partials)
//   [16384, 17408)   float dpart[NB*8*4]       (per-wave denominator partials, cg==0)
//   [17408, 17412)   unsigned counter          (blocks-done; memset to 0 each launch)
#define OFF_DPART 16384
#define OFF_CTR   17408
#define NBLK      1024

// Geometric z-window (verified absmax 0.0 in prior rounds): any positive pair
// satisfies |czq - czk| < 0.5*maxd (fp32 monotonicity: d2 >= dz^2, sqrt/div
// RN monotone). Window spans at most 2 k z-slabs. Returns first feasible zk
// clamped to [0, DD-2], or -1 if none.
__device__ __forceinline__ int z_window(float czq, float bdk, float k2, float maxd) {
    float lim = 0.500060f * maxd;
    int zk0 = -1;
    #pragma unroll
    for (int zk = 0; zk < DD; ++zk) {
        float czk = __fadd_rn(__fmul_rn(__fadd_rn((float)zk, 0.5f), bdk), k2);
        bool feas = fabsf(__fsub_rn(czq, czk)) < lim;
        if (feas && zk0 < 0) zk0 = zk;
    }
    if (zk0 > DD - 2) zk0 = DD - 2;
    return zk0;
}

typedef __attribute__((address_space(3))) void       lds_void;
typedef __attribute__((address_space(1))) const void glb_void;

// Fused kernel: block = (cg, zq, n), 1024 blocks = 4/CU (full residency).
// Stages only the FEASIBLE k z-slabs (per-slab 16 KB) into LDS via
// global_load_lds (16B, no VGPR round-trip); each thread owns one q-voxel,
// enumerates <=18 candidate k-voxels, runs the exact fp32-mirrored positivity
// test, gathers s[c] from LDS, dots with prefetched q registers, reduces.
// Last-finishing block (device atomic counter) performs the final reduction
// (bit-identical to the old final_kernel) and writes out[0].
#define CC 16
__global__ __launch_bounds__(256) void fused_kernel(
    const float* __restrict__ q, const float* __restrict__ k,
    const float* __restrict__ coord_q, const float* __restrict__ coord_k,
    float* __restrict__ partial, float* __restrict__ dpart,
    unsigned* __restrict__ counter, float* __restrict__ out)
{
    __shared__ float klds[CC][512];
    __shared__ float numsh[NB];
    __shared__ float densh[NB];
    __shared__ int   is_last;

    int t  = threadIdx.x;
    int wv = t >> 6;
    int lane = t & 63;
    int cg = blockIdx.x;          // 16 channel groups
    int zq = blockIdx.y;          // 8 q z-slabs
    int n  = blockIdx.z;
    int flat = (n * 8 + zq) * 16 + cg;
    int c0 = cg * CC;

    // Block-uniform coord math (identical fp32 ops to the verified code).
    const float* cq = coord_q + n * 6;
    const float* ck = coord_k + n * 6;
    float q0 = cq[0], q1 = cq[1], q2 = cq[2];
    float k0 = ck[0], k1 = ck[1], k2 = ck[2];
    float bwq = __fdiv_rn(__fsub_rn(cq[3], q0), (float)WW);
    float bhq = __fdiv_rn(__fsub_rn(cq[4], q1), (float)HH);
    float bdq = __fdiv_rn(__fsub_rn(cq[5], q2), (float)DD);
    float bwk = __fdiv_rn(__fsub_rn(ck[3], k0), (float)WW);
    float bhk = __fdiv_rn(__fsub_rn(ck[4], k1), (float)HH);
    float bdk = __fdiv_rn(__fsub_rn(ck[5], k2), (float)DD);
    float diagq = __fsqrt_rn(__fadd_rn(__fadd_rn(__fmul_rn(bwq, bwq), __fmul_rn(bhq, bhq)),
                                       __fmul_rn(bdq, bdq)));
    float diagk = __fsqrt_rn(__fadd_rn(__fadd_rn(__fmul_rn(bwk, bwk), __fmul_rn(bhk, bhk)),
                                       __fmul_rn(bdk, bdk)));
    float maxd = fmaxf(diagq, diagk);
    float cqz = __fadd_rn(__fmul_rn(__fadd_rn((float)zq, 0.5f), bdq), q2);

    int zk0 = z_window(cqz, bdk, k2, maxd);

    float acc = 0.0f;
    int cnt = 0;

    if (zk0 >= 0) {
        float lim = 0.500060f * maxd;

        // Per-slab feasibility with the SAME fp ops as z_window. An infeasible
        // slab cannot contain a positive (d2 >= dz^2 => dist >= 0.50006 > 0.5,
        // RN-monotone), so skipping its staging AND its gather is exact.
        float czk0 = __fadd_rn(__fmul_rn(__fadd_rn((float)zk0, 0.5f), bdk), k2);
        float czk1 = __fadd_rn(__fmul_rn(__fadd_rn((float)(zk0 + 1), 0.5f), bdk), k2);
        bool feas0 = fabsf(__fsub_rn(cqz, czk0)) < lim;
        bool feas1 = fabsf(__fsub_rn(cqz, czk1)) < lim;

        // Stage feasible k slabs -> LDS via async global_load_lds (16B chunks).
        // Chunk f = i*256 + t ; c = i*4 + wv (wave-uniform), lane-linear LDS dst.
        {
            int u = (t & 63) << 2;               // float offset within 256-row
            if (feas0) {
                const float* ksrc = k + ((size_t)(n * CH + c0)) * PP + (zk0 << 8);
                #pragma unroll
                for (int i = 0; i < 4; ++i) {
                    int c = i * 4 + wv;
                    const float* src = ksrc + (size_t)c * PP + u;
                    float* dst = &klds[c][u];
                    __builtin_amdgcn_global_load_lds((const glb_void*)src,
                                                     (lds_void*)dst, 16, 0, 0);
                }
            }
            if (feas1) {
                const float* ksrc = k + ((size_t)(n * CH + c0)) * PP + ((zk0 + 1) << 8);
                #pragma unroll
                for (int i = 0; i < 4; ++i) {
                    int c = i * 4 + wv;
                    const float* src = ksrc + (size_t)c * PP + u;
                    float* dst = &klds[c][256 + u];
                    __builtin_amdgcn_global_load_lds((const glb_void*)src,
                                                     (lds_void*)dst, 16, 0, 0);
                }
            }
        }

        // Prefetch this thread's q values (coalesced per c; latency hides under
        // the LDS staging).
        int p = (zq << 8) + t;
        float qv[CC];
        {
            const float* qcol = q + ((size_t)(n * CH + c0)) * PP + p;
            #pragma unroll
            for (int c = 0; c < CC; ++c)
                qv[c] = qcol[(size_t)c * PP];
        }

        // This thread's q-voxel center (exact fp32 chain).
        int ix = t & 15, iy = (t >> 4) & 15;
        float cqx = __fadd_rn(__fmul_rn(__fadd_rn((float)ix, 0.5f), bwq), q0);
        float cqy = __fadd_rn(__fmul_rn(__fadd_rn((float)iy, 0.5f), bhq), q1);

        // Conservative per-dim index windows; enumerated candidates get the
        // EXACT test, so over-inclusion is harmless.
        float tx = (cqx - k0) / bwk - 0.5f;
        float ty = (cqy - k1) / bhk - 0.5f;
        float rx = lim / bwk + 0.03f;
        float ry = lim / bhk + 0.03f;
        int jx0 = (int)ceilf(tx - rx);  if (jx0 < 0) jx0 = 0;
        int jx1 = (int)floorf(tx + rx); if (jx1 > WW - 1) jx1 = WW - 1;
        int jy0 = (int)ceilf(ty - ry);  if (jy0 < 0) jy0 = 0;
        int jy1 = (int)floorf(ty + ry); if (jy1 > HH - 1) jy1 = HH - 1;

        float half_maxd = 0.5f * maxd;
        float thr2 = half_maxd * half_maxd * 1.001f;   // prefilter; exact check inside

        float s[CC];
        #pragma unroll
        for (int c = 0; c < CC; ++c) s[c] = 0.0f;

        __syncthreads();   // staging complete (drains vmcnt incl. global_load_lds)

        for (int dzI = 0; dzI < 2; ++dzI) {
            if (dzI == 0 ? !feas0 : !feas1) continue;   // block-uniform skip, exact
            int jz = zk0 + dzI;
            float ckz = __fadd_rn(__fmul_rn(__fadd_rn((float)jz, 0.5f), bdk), k2);
            float dz  = __fsub_rn(cqz, ckz);
            float dz2 = __fmul_rn(dz, dz);
            for (int jy = jy0; jy <= jy1; ++jy) {
                float cky = __fadd_rn(__fmul_rn(__fadd_rn((float)jy, 0.5f), bhk), k1);
                float dy  = __fsub_rn(cqy, cky);
                float dy2 = __fmul_rn(dy, dy);
                for (int jx = jx0; jx <= jx1; ++jx) {
                    float ckx = __fadd_rn(__fmul_rn(__fadd_rn((float)jx, 0.5f), bwk), k0);
                    float dx  = __fsub_rn(cqx, ckx);
                    float dx2 = __fmul_rn(dx, dx);
                    float d2  = __fadd_rn(__fadd_rn(dx2, dy2), dz2);
                    bool pos = false;
                    if (d2 < thr2) {
                        float dist = __fdiv_rn(__fsqrt_rn(d2), maxd);
                        pos = dist < 0.5f;
                    }
                    if (pos) {
                        ++cnt;
                        int idx = (dzI << 8) + (jy << 4) + jx;
                        #pragma unroll
                        for (int c = 0; c < CC; ++c)
                            s[c] += klds[c][idx];
                    }
                }
            }
        }

        #pragma unroll
        for (int c = 0; c < CC; ++c)
            acc += qv[c] * s[c];
    }

    // Wave-shuffle reduction (no syncthreads), one agent-scope store per wave.
    int ci = cnt;
    #pragma unroll
    for (int off = 32; off > 0; off >>= 1) {
        acc += __shfl_down(acc, off, 64);
        ci  += __shfl_down(ci, off, 64);
    }
    if (lane == 0) {
        __hip_atomic_store(&partial[flat * 4 + wv], acc,
                           __ATOMIC_RELAXED, __HIP_MEMORY_SCOPE_AGENT);
        if (cg == 0)
            __hip_atomic_store(&dpart[(n * 8 + zq) * 4 + wv], (float)ci,
                               __ATOMIC_RELAXED, __HIP_MEMORY_SCOPE_AGENT);
    }
    __syncthreads();   // all 4 wave-stores of this block issued & drained

    if (t == 0) {
        __threadfence();   // make stores visible device-wide before signaling
        unsigned old = __hip_atomic_fetch_add(counter, 1u,
                                              __ATOMIC_ACQ_REL, __HIP_MEMORY_SCOPE_AGENT);
        is_last = (old == NBLK - 1) ? 1 : 0;
    }
    __syncthreads();

    if (is_last) {
        // Final reduction — bit-identical summation order to the old
        // final_kernel: wave wv handles n = wv and n = wv + 4.
        #pragma unroll
        for (int rep = 0; rep < 2; ++rep) {
            int nn = wv + rep * 4;
            float sp = 0.0f;
            #pragma unroll
            for (int i = 0; i < 8; ++i)
                sp += __hip_atomic_load(&partial[nn * 512 + i * 64 + lane],
                                        __ATOMIC_RELAXED, __HIP_MEMORY_SCOPE_AGENT);
            float sc = (lane < 32)
                ? __hip_atomic_load(&dpart[nn * 32 + lane],
                                    __ATOMIC_RELAXED, __HIP_MEMORY_SCOPE_AGENT)
                : 0.0f;
            #pragma unroll
            for (int off = 32; off > 0; off >>= 1) {
                sp += __shfl_down(sp, off, 64);
                sc += __shfl_down(sc, off, 64);
            }
            if (lane == 0) { numsh[nn] = sp; densh[nn] = sc; }
        }
        __syncthreads();
        if (t == 0) {
            float r = 0.0f;
            for (int i = 0; i < NB; ++i)
                r += numsh[i] / (densh[i] + 1e-6f);
            out[0] = -2.0f * (r / (float)NB);
        }
    }
}

extern "C" void kernel_launch(void* const* d_in, const int* in_sizes, int n_in,
                              void* d_out, int out_size, void* d_ws, size_t ws_size,
                              hipStream_t stream) {
    const float* q       = (const float*)d_in[0];
    const float* k       = (const float*)d_in[1];
    const float* coord_q = (const float*)d_in[2];
    const float* coord_k = (const float*)d_in[3];
    float* out = (float*)d_out;

    char* w = (char*)d_ws;
    float*    partial = (float*)w;
    float*    dpart   = (float*)(w + OFF_DPART);
    unsigned* counter = (unsigned*)(w + OFF_CTR);

    // Zero only the 4-byte completion counter (workspace is poisoned each
    // iteration; partial/dpart are fully overwritten by all 1024 blocks).
    hipMemsetAsync((void*)counter, 0, sizeof(unsigned), stream);

    fused_kernel<<<dim3(CH / CC, DD, NB), 256, 0, stream>>>(
        q, k, coord_q, coord_k, partial, dpart, counter, out);
}

// Round 2
// 80.557 us; speedup vs baseline: 1.5758x; 1.5758x over previous
//
#include <hip/hip_runtime.h>
#include <cstdint>
#include <cstddef>

// Problem constants (from reference setup_inputs)
#define NB 8
#define CH 256
#define DD 8
#define HH 16
#define WW 16
#define PP 2048          // D*H*W ; one z-slab = HH*WW = 256 voxels

// Workspace layout (bytes):
//   [0,     16384)   float partial[NB*8*16*4]  (per-wave numerator partials)
//   [16384, 17408)   float dpart[NB*8*4]       (per-wave denominator partials, cg==0)
#define OFF_DPART 16384

// Geometric z-window (verified absmax 0.0 across rounds): any positive pair
// satisfies |czq - czk| < 0.5*maxd (fp32 monotonicity: d2 >= dz^2, sqrt/div
// RN monotone). Window spans at most 2 k z-slabs. Returns first feasible zk
// clamped to [0, DD-2], or -1 if none.
__device__ __forceinline__ int z_window(float czq, float bdk, float k2, float maxd) {
    float lim = 0.500060f * maxd;
    int zk0 = -1;
    #pragma unroll
    for (int zk = 0; zk < DD; ++zk) {
        float czk = __fadd_rn(__fmul_rn(__fadd_rn((float)zk, 0.5f), bdk), k2);
        bool feas = fabsf(__fsub_rn(czq, czk)) < lim;
        if (feas && zk0 < 0) zk0 = zk;
    }
    if (zk0 > DD - 2) zk0 = DD - 2;
    return zk0;
}

typedef __attribute__((address_space(3))) void       lds_void;
typedef __attribute__((address_space(1))) const void glb_void;

// Fused kernel: block = (cg, zq, n), 1024 blocks = 4/CU (full residency,
// LDS 32 KB -> 4 blocks/CU). Stages only the FEASIBLE k z-slabs into LDS via
// async global_load_lds (16B chunks, no VGPR round-trip). Each thread owns
// one q-voxel, enumerates <=18 candidate k-voxels via per-dim index windows,
// runs the exact fp32-mirrored positivity test, gathers s[c] from LDS, dots
// with prefetched q registers, wave-shuffle-reduces to one store per wave.
// NO cross-block fences here (R1 lesson: per-block agent-scope wbl2/inv
// invalidated L2 1024x -> latency collapse). Kernel-boundary ordering makes
// the partials visible to final_kernel.
#define CC 16
__global__ __launch_bounds__(256) void fused_kernel(
    const float* __restrict__ q, const float* __restrict__ k,
    const float* __restrict__ coord_q, const float* __restrict__ coord_k,
    float* __restrict__ partial, float* __restrict__ dpart)
{
    __shared__ float klds[CC][512];

    int t  = threadIdx.x;
    int wv = t >> 6;
    int lane = t & 63;
    int cg = blockIdx.x;          // 16 channel groups
    int zq = blockIdx.y;          // 8 q z-slabs
    int n  = blockIdx.z;
    int flat = (n * 8 + zq) * 16 + cg;
    int c0 = cg * CC;

    // Block-uniform coord math (identical fp32 ops to the verified code).
    const float* cq = coord_q + n * 6;
    const float* ck = coord_k + n * 6;
    float q0 = cq[0], q1 = cq[1], q2 = cq[2];
    float k0 = ck[0], k1 = ck[1], k2 = ck[2];
    float bwq = __fdiv_rn(__fsub_rn(cq[3], q0), (float)WW);
    float bhq = __fdiv_rn(__fsub_rn(cq[4], q1), (float)HH);
    float bdq = __fdiv_rn(__fsub_rn(cq[5], q2), (float)DD);
    float bwk = __fdiv_rn(__fsub_rn(ck[3], k0), (float)WW);
    float bhk = __fdiv_rn(__fsub_rn(ck[4], k1), (float)HH);
    float bdk = __fdiv_rn(__fsub_rn(ck[5], k2), (float)DD);
    float diagq = __fsqrt_rn(__fadd_rn(__fadd_rn(__fmul_rn(bwq, bwq), __fmul_rn(bhq, bhq)),
                                       __fmul_rn(bdq, bdq)));
    float diagk = __fsqrt_rn(__fadd_rn(__fadd_rn(__fmul_rn(bwk, bwk), __fmul_rn(bhk, bhk)),
                                       __fmul_rn(bdk, bdk)));
    float maxd = fmaxf(diagq, diagk);
    float cqz = __fadd_rn(__fmul_rn(__fadd_rn((float)zq, 0.5f), bdq), q2);

    int zk0 = z_window(cqz, bdk, k2, maxd);

    float acc = 0.0f;
    int cnt = 0;

    if (zk0 >= 0) {
        float lim = 0.500060f * maxd;

        // Per-slab feasibility with the SAME fp ops as z_window. An infeasible
        // slab cannot contain a positive (d2 >= dz^2 => dist >= 0.50006 > 0.5,
        // RN-monotone), so skipping its staging AND its gather is exact
        // (verified absmax 0.0 in R1).
        float czk0 = __fadd_rn(__fmul_rn(__fadd_rn((float)zk0, 0.5f), bdk), k2);
        float czk1 = __fadd_rn(__fmul_rn(__fadd_rn((float)(zk0 + 1), 0.5f), bdk), k2);
        bool feas0 = fabsf(__fsub_rn(cqz, czk0)) < lim;
        bool feas1 = fabsf(__fsub_rn(cqz, czk1)) < lim;

        // Stage feasible k slabs -> LDS via async global_load_lds (16B chunks).
        // Per wave: c = i*4 + wv (wave-uniform row), LDS dst lane-linear
        // (base + lane*16B) which matches the HW write pattern exactly.
        {
            int u = (t & 63) << 2;               // float offset within 256-row
            if (feas0) {
                const float* ksrc = k + ((size_t)(n * CH + c0)) * PP + (zk0 << 8);
                #pragma unroll
                for (int i = 0; i < 4; ++i) {
                    int c = i * 4 + wv;
                    const float* src = ksrc + (size_t)c * PP + u;
                    float* dst = &klds[c][u];
                    __builtin_amdgcn_global_load_lds((const glb_void*)src,
                                                     (lds_void*)dst, 16, 0, 0);
                }
            }
            if (feas1) {
                const float* ksrc = k + ((size_t)(n * CH + c0)) * PP + ((zk0 + 1) << 8);
                #pragma unroll
                for (int i = 0; i < 4; ++i) {
                    int c = i * 4 + wv;
                    const float* src = ksrc + (size_t)c * PP + u;
                    float* dst = &klds[c][256 + u];
                    __builtin_amdgcn_global_load_lds((const glb_void*)src,
                                                     (lds_void*)dst, 16, 0, 0);
                }
            }
        }

        // Prefetch this thread's q values (coalesced per c; latency hides under
        // the async LDS staging).
        int p = (zq << 8) + t;
        float qv[CC];
        {
            const float* qcol = q + ((size_t)(n * CH + c0)) * PP + p;
            #pragma unroll
            for (int c = 0; c < CC; ++c)
                qv[c] = qcol[(size_t)c * PP];
        }

        // This thread's q-voxel center (exact fp32 chain).
        int ix = t & 15, iy = (t >> 4) & 15;
        float cqx = __fadd_rn(__fmul_rn(__fadd_rn((float)ix, 0.5f), bwq), q0);
        float cqy = __fadd_rn(__fmul_rn(__fadd_rn((float)iy, 0.5f), bhq), q1);

        // Conservative per-dim index windows; enumerated candidates get the
        // EXACT test, so over-inclusion is harmless.
        float tx = (cqx - k0) / bwk - 0.5f;
        float ty = (cqy - k1) / bhk - 0.5f;
        float rx = lim / bwk + 0.03f;
        float ry = lim / bhk + 0.03f;
        int jx0 = (int)ceilf(tx - rx);  if (jx0 < 0) jx0 = 0;
        int jx1 = (int)floorf(tx + rx); if (jx1 > WW - 1) jx1 = WW - 1;
        int jy0 = (int)ceilf(ty - ry);  if (jy0 < 0) jy0 = 0;
        int jy1 = (int)floorf(ty + ry); if (jy1 > HH - 1) jy1 = HH - 1;

        float half_maxd = 0.5f * maxd;
        float thr2 = half_maxd * half_maxd * 1.001f;   // prefilter; exact check inside

        float s[CC];
        #pragma unroll
        for (int c = 0; c < CC; ++c) s[c] = 0.0f;

        __syncthreads();   // staging complete (drains vmcnt incl. global_load_lds)

        for (int dzI = 0; dzI < 2; ++dzI) {
            if (dzI == 0 ? !feas0 : !feas1) continue;   // block-uniform skip, exact
            int jz = zk0 + dzI;
            float ckz = __fadd_rn(__fmul_rn(__fadd_rn((float)jz, 0.5f), bdk), k2);
            float dz  = __fsub_rn(cqz, ckz);
            float dz2 = __fmul_rn(dz, dz);
            for (int jy = jy0; jy <= jy1; ++jy) {
                float cky = __fadd_rn(__fmul_rn(__fadd_rn((float)jy, 0.5f), bhk), k1);
                float dy  = __fsub_rn(cqy, cky);
                float dy2 = __fmul_rn(dy, dy);
                for (int jx = jx0; jx <= jx1; ++jx) {
                    float ckx = __fadd_rn(__fmul_rn(__fadd_rn((float)jx, 0.5f), bwk), k0);
                    float dx  = __fsub_rn(cqx, ckx);
                    float dx2 = __fmul_rn(dx, dx);
                    float d2  = __fadd_rn(__fadd_rn(dx2, dy2), dz2);
                    bool pos = false;
                    if (d2 < thr2) {
                        float dist = __fdiv_rn(__fsqrt_rn(d2), maxd);
                        pos = dist < 0.5f;
                    }
                    if (pos) {
                        ++cnt;
                        int idx = (dzI << 8) + (jy << 4) + jx;
                        #pragma unroll
                        for (int c = 0; c < CC; ++c)
                            s[c] += klds[c][idx];
                    }
                }
            }
        }

        #pragma unroll
        for (int c = 0; c < CC; ++c)
            acc += qv[c] * s[c];
    }

    // Wave-shuffle reduction (no syncthreads), one plain store per wave.
    int ci = cnt;
    #pragma unroll
    for (int off = 32; off > 0; off >>= 1) {
        acc += __shfl_down(acc, off, 64);
        ci  += __shfl_down(ci, off, 64);
    }
    if (lane == 0) {
        partial[flat * 4 + wv] = acc;
        if (cg == 0) dpart[(n * 8 + zq) * 4 + wv] = (float)ci;
    }
}

// Final: one wave per batch sums 512 numerator partials + 32 denominator
// partials; thread 0 combines. (Separate launch: kernel-boundary ordering
// provides cross-XCD visibility with ONE amortized cache op — R1 lesson.)
__global__ __launch_bounds__(512) void final_kernel(const float* __restrict__ partial,
                                                    const float* __restrict__ dpart,
                                                    float* __restrict__ out)
{
    __shared__ float numsh[NB];
    __shared__ float densh[NB];
    int t = threadIdx.x;
    int n = t >> 6, lane = t & 63;

    float sp = 0.0f;
    #pragma unroll
    for (int i = 0; i < 8; ++i)
        sp += partial[n * 512 + i * 64 + lane];
    float sc = (lane < 32) ? dpart[n * 32 + lane] : 0.0f;
    #pragma unroll
    for (int off = 32; off > 0; off >>= 1) {
        sp += __shfl_down(sp, off, 64);
        sc += __shfl_down(sc, off, 64);
    }
    if (lane == 0) { numsh[n] = sp; densh[n] = sc; }
    __syncthreads();
    if (t == 0) {
        float r = 0.0f;
        for (int i = 0; i < NB; ++i)
            r += numsh[i] / (densh[i] + 1e-6f);
        out[0] = -2.0f * (r / (float)NB);
    }
}

extern "C" void kernel_launch(void* const* d_in, const int* in_sizes, int n_in,
                              void* d_out, int out_size, void* d_ws, size_t ws_size,
                              hipStream_t stream) {
    const float* q       = (const float*)d_in[0];
    const float* k       = (const float*)d_in[1];
    const float* coord_q = (const float*)d_in[2];
    const float* coord_k = (const float*)d_in[3];
    float* out = (float*)d_out;

    char* w = (char*)d_ws;
    float* partial = (float*)w;
    float* dpart   = (float*)(w + OFF_DPART);

    fused_kernel<<<dim3(CH / CC, DD, NB), 256, 0, stream>>>(q, k, coord_q, coord_k,
                                                            partial, dpart);
    final_kernel<<<1, 512, 0, stream>>>(partial, dpart, out);
}

// Round 3
// 80.119 us; speedup vs baseline: 1.5844x; 1.0055x over previous
//
#include <hip/hip_runtime.h>
#include <cstdint>
#include <cstddef>

// Problem constants (from reference setup_inputs)
#define NB 8
#define CH 256
#define DD 8
#define HH 16
#define WW 16
#define PP 2048          // D*H*W ; one z-slab = HH*WW = 256 voxels

// Workspace layout (bytes):
//   [0,     16384)   float partial[NB*8*16*4]  (per-wave numerator partials)
//   [16384, 17408)   float dpart[NB*8*4]       (per-wave denominator partials, cg==0)
#define OFF_DPART 16384

// Geometric z-window (verified absmax 0.0 across rounds): any positive pair
// satisfies |czq - czk| < 0.5*maxd (fp32 monotonicity: d2 >= dz^2, sqrt/div
// RN monotone). Window spans at most 2 k z-slabs. Returns first feasible zk
// clamped to [0, DD-2], or -1 if none.
__device__ __forceinline__ int z_window(float czq, float bdk, float k2, float maxd) {
    float lim = 0.500060f * maxd;
    int zk0 = -1;
    #pragma unroll
    for (int zk = 0; zk < DD; ++zk) {
        float czk = __fadd_rn(__fmul_rn(__fadd_rn((float)zk, 0.5f), bdk), k2);
        bool feas = fabsf(__fsub_rn(czq, czk)) < lim;
        if (feas && zk0 < 0) zk0 = zk;
    }
    if (zk0 > DD - 2) zk0 = DD - 2;
    return zk0;
}

// Fused kernel: block = (cg, zq, n), 1024 blocks = 4/CU. LDS holds the k tile
// TRANSPOSED: klds[p'][c] (rows = 512 k-voxels over 2 slabs, cols = 16 ch,
// 64 B/row) so one candidate's 16 channels are 4x ds_read_b128 instead of
// 16x ds_read_b32. Each lane builds a bitmask of its true positives first
// (pure VALU, hidden under staging-load latency), then gathers ONLY positives
// via a ctz loop (wave executes max-over-lanes ~7 iters, not all ~18 window
// candidates) -- ~5x less LDS gather traffic than the branchy per-candidate
// version. Accumulation order (dz,jy,jx ascending; c ascending) is preserved
// bit-exactly vs the verified R2 kernel. No cross-block fences (R1 lesson).
#define CC 16
__global__ __launch_bounds__(256) void fused_kernel(
    const float* __restrict__ q, const float* __restrict__ k,
    const float* __restrict__ coord_q, const float* __restrict__ coord_k,
    float* __restrict__ partial, float* __restrict__ dpart)
{
    __shared__ __align__(16) float klds[512][CC];   // [p' (2 slabs)][c]

    int t  = threadIdx.x;
    int wv = t >> 6;
    int lane = t & 63;
    int cg = blockIdx.x;          // 16 channel groups
    int zq = blockIdx.y;          // 8 q z-slabs
    int n  = blockIdx.z;
    int flat = (n * 8 + zq) * 16 + cg;
    int c0 = cg * CC;

    // Block-uniform coord math (identical fp32 ops to the verified code).
    const float* cq = coord_q + n * 6;
    const float* ck = coord_k + n * 6;
    float q0 = cq[0], q1 = cq[1], q2 = cq[2];
    float k0 = ck[0], k1 = ck[1], k2 = ck[2];
    float bwq = __fdiv_rn(__fsub_rn(cq[3], q0), (float)WW);
    float bhq = __fdiv_rn(__fsub_rn(cq[4], q1), (float)HH);
    float bdq = __fdiv_rn(__fsub_rn(cq[5], q2), (float)DD);
    float bwk = __fdiv_rn(__fsub_rn(ck[3], k0), (float)WW);
    float bhk = __fdiv_rn(__fsub_rn(ck[4], k1), (float)HH);
    float bdk = __fdiv_rn(__fsub_rn(ck[5], k2), (float)DD);
    float diagq = __fsqrt_rn(__fadd_rn(__fadd_rn(__fmul_rn(bwq, bwq), __fmul_rn(bhq, bhq)),
                                       __fmul_rn(bdq, bdq)));
    float diagk = __fsqrt_rn(__fadd_rn(__fadd_rn(__fmul_rn(bwk, bwk), __fmul_rn(bhk, bhk)),
                                       __fmul_rn(bdk, bdk)));
    float maxd = fmaxf(diagq, diagk);
    float cqz = __fadd_rn(__fmul_rn(__fadd_rn((float)zq, 0.5f), bdq), q2);

    int zk0 = z_window(cqz, bdk, k2, maxd);

    float acc = 0.0f;
    int cnt = 0;

    if (zk0 >= 0) {                // block-uniform branch (syncthreads-safe)
        float lim = 0.500060f * maxd;

        // Per-slab feasibility with the SAME fp ops as z_window (exact skip,
        // verified absmax 0.0 in R1/R2).
        float czk0 = __fadd_rn(__fmul_rn(__fadd_rn((float)zk0, 0.5f), bdk), k2);
        float czk1 = __fadd_rn(__fmul_rn(__fadd_rn((float)(zk0 + 1), 0.5f), bdk), k2);
        bool feas0 = fabsf(__fsub_rn(cqz, czk0)) < lim;
        bool feas1 = fabsf(__fsub_rn(cqz, czk1)) < lim;

        // --- Stage 1: issue all staging global loads into registers.
        // Thread t owns LDS rows {i*64 + (t>>2)} at c-quad (t&3): the
        // ds_write_b128 addresses are base + t*16 (dense, conflict-free).
        // Global src per scalar load: 4x 64B segments per wave (L2/L3-hot).
        int pr = t >> 2, cquad = t & 3;
        const float* kbase = k + ((size_t)(n * CH + c0)) * PP;
        float st0[16], st1[16];
        if (feas0) {
            const float* g = kbase + (zk0 << 8);
            #pragma unroll
            for (int i = 0; i < 4; ++i)
                #pragma unroll
                for (int j = 0; j < 4; ++j)
                    st0[i * 4 + j] = g[(size_t)(cquad * 4 + j) * PP + (i * 64 + pr)];
        }
        if (feas1) {
            const float* g = kbase + ((zk0 + 1) << 8);
            #pragma unroll
            for (int i = 0; i < 4; ++i)
                #pragma unroll
                for (int j = 0; j < 4; ++j)
                    st1[i * 4 + j] = g[(size_t)(cquad * 4 + j) * PP + (i * 64 + pr)];
        }

        // q prefetch (consumed last -> issued after staging loads).
        int p = (zq << 8) + t;
        float qv[CC];
        {
            const float* qcol = q + ((size_t)(n * CH + c0)) * PP + p;
            #pragma unroll
            for (int c = 0; c < CC; ++c)
                qv[c] = qcol[(size_t)c * PP];
        }

        // --- Stage 2: window bounds + positive BITMASK build (pure VALU,
        // overlaps the in-flight staging loads). Identical fp32 test chain
        // as the verified kernel -> identical positive set; bit order
        // (jy,jx) ascending within each dz = original iteration order.
        int ix = t & 15, iy = (t >> 4) & 15;
        float cqx = __fadd_rn(__fmul_rn(__fadd_rn((float)ix, 0.5f), bwq), q0);
        float cqy = __fadd_rn(__fmul_rn(__fadd_rn((float)iy, 0.5f), bhq), q1);

        float tx = (cqx - k0) / bwk - 0.5f;
        float ty = (cqy - k1) / bhk - 0.5f;
        float rx = lim / bwk + 0.03f;
        float ry = lim / bhk + 0.03f;
        int jx0 = (int)ceilf(tx - rx);  if (jx0 < 0) jx0 = 0;
        int jx1 = (int)floorf(tx + rx); if (jx1 > WW - 1) jx1 = WW - 1;
        int jy0 = (int)ceilf(ty - ry);  if (jy0 < 0) jy0 = 0;
        int jy1 = (int)floorf(ty + ry); if (jy1 > HH - 1) jy1 = HH - 1;
        // Geometry bound: rx,ry ~= 1.25 bins -> spans <= 4 (< 8), so the
        // (oy<<3)|ox bit encoding below never exceeds bit 63.

        float half_maxd = 0.5f * maxd;
        float thr2 = half_maxd * half_maxd * 1.001f;   // prefilter; exact check inside

        unsigned long long m0 = 0ull, m1 = 0ull;
        for (int dzI = 0; dzI < 2; ++dzI) {
            if (dzI == 0 ? !feas0 : !feas1) continue;   // block-uniform, exact
            int jz = zk0 + dzI;
            float ckz = __fadd_rn(__fmul_rn(__fadd_rn((float)jz, 0.5f), bdk), k2);
            float dzf = __fsub_rn(cqz, ckz);
            float dz2 = __fmul_rn(dzf, dzf);
            unsigned long long mm = 0ull;
            for (int jy = jy0; jy <= jy1; ++jy) {
                float cky = __fadd_rn(__fmul_rn(__fadd_rn((float)jy, 0.5f), bhk), k1);
                float dy  = __fsub_rn(cqy, cky);
                float dy2 = __fmul_rn(dy, dy);
                for (int jx = jx0; jx <= jx1; ++jx) {
                    float ckx = __fadd_rn(__fmul_rn(__fadd_rn((float)jx, 0.5f), bwk), k0);
                    float dx  = __fsub_rn(cqx, ckx);
                    float dx2 = __fmul_rn(dx, dx);
                    float d2  = __fadd_rn(__fadd_rn(dx2, dy2), dz2);
                    bool pos = false;
                    if (d2 < thr2) {
                        float dist = __fdiv_rn(__fsqrt_rn(d2), maxd);
                        pos = dist < 0.5f;
                    }
                    if (pos)
                        mm |= 1ull << (((jy - jy0) << 3) | (jx - jx0));
                }
            }
            if (dzI == 0) m0 = mm; else m1 = mm;
        }

        // --- Stage 3: transpose-write staged k into LDS (dense b128, t*16).
        if (feas0) {
            #pragma unroll
            for (int i = 0; i < 4; ++i) {
                float4 v = make_float4(st0[i*4+0], st0[i*4+1], st0[i*4+2], st0[i*4+3]);
                *reinterpret_cast<float4*>(&klds[i * 64 + pr][cquad * 4]) = v;
            }
        }
        if (feas1) {
            #pragma unroll
            for (int i = 0; i < 4; ++i) {
                float4 v = make_float4(st1[i*4+0], st1[i*4+1], st1[i*4+2], st1[i*4+3]);
                *reinterpret_cast<float4*>(&klds[256 + i * 64 + pr][cquad * 4]) = v;
            }
        }

        float s[CC];
        #pragma unroll
        for (int c = 0; c < CC; ++c) s[c] = 0.0f;

        __syncthreads();   // staging visible

        // --- Stage 4: positives-only gather. Per positive: 4x ds_read_b128
        // (row = candidate voxel, 64 B of channels) + 16 adds in ascending c
        // order -- bit-identical accumulation sequence to the verified loop.
        while (m0) {
            int slot = __builtin_ctzll(m0);
            m0 &= m0 - 1;
            int idx = ((jy0 + (slot >> 3)) << 4) + (jx0 + (slot & 7));
            const float4* r = reinterpret_cast<const float4*>(&klds[idx][0]);
            float4 v0 = r[0], v1 = r[1], v2 = r[2], v3 = r[3];
            s[0]  += v0.x; s[1]  += v0.y; s[2]  += v0.z; s[3]  += v0.w;
            s[4]  += v1.x; s[5]  += v1.y; s[6]  += v1.z; s[7]  += v1.w;
            s[8]  += v2.x; s[9]  += v2.y; s[10] += v2.z; s[11] += v2.w;
            s[12] += v3.x; s[13] += v3.y; s[14] += v3.z; s[15] += v3.w;
            ++cnt;
        }
        while (m1) {
            int slot = __builtin_ctzll(m1);
            m1 &= m1 - 1;
            int idx = 256 + (((jy0 + (slot >> 3)) << 4) + (jx0 + (slot & 7)));
            const float4* r = reinterpret_cast<const float4*>(&klds[idx][0]);
            float4 v0 = r[0], v1 = r[1], v2 = r[2], v3 = r[3];
            s[0]  += v0.x; s[1]  += v0.y; s[2]  += v0.z; s[3]  += v0.w;
            s[4]  += v1.x; s[5]  += v1.y; s[6]  += v1.z; s[7]  += v1.w;
            s[8]  += v2.x; s[9]  += v2.y; s[10] += v2.z; s[11] += v2.w;
            s[12] += v3.x; s[13] += v3.y; s[14] += v3.z; s[15] += v3.w;
            ++cnt;
        }

        #pragma unroll
        for (int c = 0; c < CC; ++c)
            acc += qv[c] * s[c];
    }

    // Wave-shuffle reduction (no syncthreads), one plain store per wave.
    int ci = cnt;
    #pragma unroll
    for (int off = 32; off > 0; off >>= 1) {
        acc += __shfl_down(acc, off, 64);
        ci  += __shfl_down(ci, off, 64);
    }
    if (lane == 0) {
        partial[flat * 4 + wv] = acc;
        if (cg == 0) dpart[(n * 8 + zq) * 4 + wv] = (float)ci;
    }
}

// Final: one wave per batch sums 512 numerator partials + 32 denominator
// partials; thread 0 combines. (Separate launch: kernel-boundary ordering
// provides cross-XCD visibility with ONE amortized cache op — R1 lesson.)
__global__ __launch_bounds__(512) void final_kernel(const float* __restrict__ partial,
                                                    const float* __restrict__ dpart,
                                                    float* __restrict__ out)
{
    __shared__ float numsh[NB];
    __shared__ float densh[NB];
    int t = threadIdx.x;
    int n = t >> 6, lane = t & 63;

    float sp = 0.0f;
    #pragma unroll
    for (int i = 0; i < 8; ++i)
        sp += partial[n * 512 + i * 64 + lane];
    float sc = (lane < 32) ? dpart[n * 32 + lane] : 0.0f;
    #pragma unroll
    for (int off = 32; off > 0; off >>= 1) {
        sp += __shfl_down(sp, off, 64);
        sc += __shfl_down(sc, off, 64);
    }
    if (lane == 0) { numsh[n] = sp; densh[n] = sc; }
    __syncthreads();
    if (t == 0) {
        float r = 0.0f;
        for (int i = 0; i < NB; ++i)
            r += numsh[i] / (densh[i] + 1e-6f);
        out[0] = -2.0f * (r / (float)NB);
    }
}

extern "C" void kernel_launch(void* const* d_in, const int* in_sizes, int n_in,
                              void* d_out, int out_size, void* d_ws, size_t ws_size,
                              hipStream_t stream) {
    const float* q       = (const float*)d_in[0];
    const float* k       = (const float*)d_in[1];
    const float* coord_q = (const float*)d_in[2];
    const float* coord_k = (const float*)d_in[3];
    float* out = (float*)d_out;

    char* w = (char*)d_ws;
    float* partial = (float*)w;
    float* dpart   = (float*)(w + OFF_DPART);

    fused_kernel<<<dim3(CH / CC, DD, NB), 256, 0, stream>>>(q, k, coord_q, coord_k,
                                                            partial, dpart);
    final_kernel<<<1, 512, 0, stream>>>(partial, dpart, out);
}